// Round 9
// baseline (9050.369 us; speedup 1.0000x reference)
//
#include <hip/hip_runtime.h>

typedef _Float16 f16;
typedef _Float16 f16x8 __attribute__((ext_vector_type(8)));
typedef float    f32x4 __attribute__((ext_vector_type(4)));

#define NSTEP 2048
#define HID   512
#define BATCH 32
#define SEQL  2048
#define NCOOP 8            // cooperating blocks in the recurrence

// ---------------------------------------------------------------------------
// One-time W_xh f32->f16 conversion (r8, measured win) + zero the coop-sync
// area (hstate[0] 32 KiB + padded flags 512 B) — stream-ordered before rnn,
// re-runs on every graph replay so the flag protocol restarts cleanly.
// ---------------------------------------------------------------------------
__global__ __launch_bounds__(256, 4) void wcvt_kernel(
    const float* __restrict__ W, f16* __restrict__ Wf,
    unsigned int* __restrict__ hz, unsigned int* __restrict__ fz)
{
    int gid = blockIdx.x * 256 + threadIdx.x;     // 0..32767
    int i = gid * 8;
    float4 a0 = *(const float4*)(W + i);
    float4 a1 = *(const float4*)(W + i + 4);
    f16x8 h;
    h[0] = (f16)a0.x; h[1] = (f16)a0.y; h[2] = (f16)a0.z; h[3] = (f16)a0.w;
    h[4] = (f16)a1.x; h[5] = (f16)a1.y; h[6] = (f16)a1.z; h[7] = (f16)a1.w;
    *(f16x8*)&Wf[i] = h;
    if (gid < 8192)      hz[gid] = 0u;            // hstate[0] = 0  (h0)
    else if (gid < 8320) fz[gid - 8192] = 0u;     // flags = 0
}

// ---------------------------------------------------------------------------
// Phase 1: xproj[m][n] = sum_k x[m][k] * Wxh[n][k] + bias[n], f16 out (r8).
// ---------------------------------------------------------------------------
#define P1_AS 40   // padded lds stride (f16); 80B = 16B-aligned

__global__ __launch_bounds__(256, 2) void xproj_f16_kernel(
    const float* __restrict__ x, const f16* __restrict__ Wf16,
    const float* __restrict__ bxh, const float* __restrict__ bhh,
    const float* __restrict__ bh, f16* __restrict__ xp)
{
    __shared__ __align__(16) f16 As[64 * P1_AS];
    __shared__ __align__(16) f16 Bs[512 * P1_AS];

    const int t = threadIdx.x;
    const int wave = t >> 6, lane = t & 63;
    const size_t mbase = (size_t)blockIdx.x * 64;

    f32x4 acc[4][8];
#pragma unroll
    for (int i = 0; i < 4; i++)
#pragma unroll
        for (int j = 0; j < 8; j++) acc[i][j] = (f32x4){0.f, 0.f, 0.f, 0.f};

    const int r_st = t >> 2;
    const int koff = (t & 3) * 8;

    for (int k0 = 0; k0 < 512; k0 += 32) {
        __syncthreads();
        {   // stage A (f32 -> f16, small)
            const float* src = x + (mbase + r_st) * 512 + k0 + koff;
            float4 a0 = *(const float4*)src;
            float4 a1 = *(const float4*)(src + 4);
            f16x8 h;
            h[0] = (f16)a0.x; h[1] = (f16)a0.y; h[2] = (f16)a0.z; h[3] = (f16)a0.w;
            h[4] = (f16)a1.x; h[5] = (f16)a1.y; h[6] = (f16)a1.z; h[7] = (f16)a1.w;
            *(f16x8*)&As[r_st * P1_AS + koff] = h;
        }
#pragma unroll
        for (int i = 0; i < 8; i++) {   // stage B: pure f16 copy
            int n = r_st + i * 64;
            *(f16x8*)&Bs[n * P1_AS + koff] =
                *(const f16x8*)(Wf16 + (size_t)n * 512 + k0 + koff);
        }
        __syncthreads();

        f16x8 af[4];
#pragma unroll
        for (int rt = 0; rt < 4; rt++)
            af[rt] = *(const f16x8*)&As[(rt * 16 + (lane & 15)) * P1_AS + (lane >> 4) * 8];
#pragma unroll
        for (int ct = 0; ct < 8; ct++) {
            f16x8 bf = *(const f16x8*)&Bs[((wave * 8 + ct) * 16 + (lane & 15)) * P1_AS + (lane >> 4) * 8];
#pragma unroll
            for (int rt = 0; rt < 4; rt++)
                acc[rt][ct] = __builtin_amdgcn_mfma_f32_16x16x32_f16(af[rt], bf, acc[rt][ct], 0, 0, 0);
        }
    }

#pragma unroll
    for (int ct = 0; ct < 8; ct++) {
        int n = wave * 128 + ct * 16 + (lane & 15);
        float bias = bxh[n] + bhh[n] + bh[n];
#pragma unroll
        for (int rt = 0; rt < 4; rt++) {
#pragma unroll
            for (int r = 0; r < 4; r++) {
                size_t m = mbase + rt * 16 + (lane >> 4) * 4 + r;
                xp[m * 512 + n] = (f16)(acc[rt][ct][r] + bias);
            }
        }
    }
}

__global__ __launch_bounds__(256, 2) void xproj_kernel(     // f32-B fallback
    const float* __restrict__ x, const float* __restrict__ Wxh,
    const float* __restrict__ bxh, const float* __restrict__ bhh,
    const float* __restrict__ bh, f16* __restrict__ xp)
{
    __shared__ __align__(16) f16 As[64 * P1_AS];
    __shared__ __align__(16) f16 Bs[512 * P1_AS];
    const int t = threadIdx.x;
    const int wave = t >> 6, lane = t & 63;
    const size_t mbase = (size_t)blockIdx.x * 64;
    f32x4 acc[4][8];
#pragma unroll
    for (int i = 0; i < 4; i++)
#pragma unroll
        for (int j = 0; j < 8; j++) acc[i][j] = (f32x4){0.f, 0.f, 0.f, 0.f};
    const int r_st = t >> 2;
    const int koff = (t & 3) * 8;
    for (int k0 = 0; k0 < 512; k0 += 32) {
        __syncthreads();
        {
            const float* src = x + (mbase + r_st) * 512 + k0 + koff;
            float4 a0 = *(const float4*)src;
            float4 a1 = *(const float4*)(src + 4);
            f16x8 h;
            h[0] = (f16)a0.x; h[1] = (f16)a0.y; h[2] = (f16)a0.z; h[3] = (f16)a0.w;
            h[4] = (f16)a1.x; h[5] = (f16)a1.y; h[6] = (f16)a1.z; h[7] = (f16)a1.w;
            *(f16x8*)&As[r_st * P1_AS + koff] = h;
        }
#pragma unroll
        for (int i = 0; i < 8; i++) {
            int n = r_st + i * 64;
            const float* src = Wxh + (size_t)n * 512 + k0 + koff;
            float4 b0 = *(const float4*)src;
            float4 b1 = *(const float4*)(src + 4);
            f16x8 h;
            h[0] = (f16)b0.x; h[1] = (f16)b0.y; h[2] = (f16)b0.z; h[3] = (f16)b0.w;
            h[4] = (f16)b1.x; h[5] = (f16)b1.y; h[6] = (f16)b1.z; h[7] = (f16)b1.w;
            *(f16x8*)&Bs[n * P1_AS + koff] = h;
        }
        __syncthreads();
        f16x8 af[4];
#pragma unroll
        for (int rt = 0; rt < 4; rt++)
            af[rt] = *(const f16x8*)&As[(rt * 16 + (lane & 15)) * P1_AS + (lane >> 4) * 8];
#pragma unroll
        for (int ct = 0; ct < 8; ct++) {
            f16x8 bf = *(const f16x8*)&Bs[((wave * 8 + ct) * 16 + (lane & 15)) * P1_AS + (lane >> 4) * 8];
#pragma unroll
            for (int rt = 0; rt < 4; rt++)
                acc[rt][ct] = __builtin_amdgcn_mfma_f32_16x16x32_f16(af[rt], bf, acc[rt][ct], 0, 0, 0);
        }
    }
#pragma unroll
    for (int ct = 0; ct < 8; ct++) {
        int n = wave * 128 + ct * 16 + (lane & 15);
        float bias = bxh[n] + bhh[n] + bh[n];
#pragma unroll
        for (int rt = 0; rt < 4; rt++) {
#pragma unroll
            for (int r = 0; r < 4; r++) {
                size_t m = mbase + rt * 16 + (lane >> 4) * 4 + r;
                xp[m * 512 + n] = (f16)(acc[rt][ct][r] + bias);
            }
        }
    }
}

// ---------------------------------------------------------------------------
// Phase 2 (NEW): cooperative recurrence — 8 blocks x 256 threads, cols split.
//
// Paradigm change (r3-r8 arithmetic): the per-batch-block structure issues
// 512 mfma/step/CU with 16x-redundant A-rows (all = h) — its MFMA-issue bound
// (2483 cyc/step) is why r0 = 2447 us is its ceiling.  Packing 32 BATCHES
// into the MFMA M-dim removes the redundancy: 1024 useful mfma/step device-
// wide.  G=8 blocks each own 64 cols x all 32 batches:
//   wave w: Mt = w&1 (batches Mt*16..+15), ct-pair p = w>>1 (cols p*32..+31)
//   B-frags 2x16 = 128 regs/thread (the register wall r5-r7 hit is gone:
//   512 KB weights / 8 CUs / 256 thr = 128 regs).  32 mfma/wave/step.
// h exchange via global hstate[2][32][512] (LLC-resident) + per-block
// monotonic step-flags with agent-scope acquire/release atomics (handles
// cross-XCD L2 non-coherence).  Race-freedom: spin(flags>=s) at step s
// guarantees every block finished READING hstate[(s-1)&1] (its reads
// happen-before its flag publish), so overwriting it at step s+1 is safe.
// Deadlock-freedom: monotonic flags, 8 blocks trivially co-resident.
// ---------------------------------------------------------------------------
__global__ __launch_bounds__(256, 1) void rnn_coop_kernel(
    const float* __restrict__ Whh, const f16* __restrict__ xp,
    f16* __restrict__ hstate, unsigned int* __restrict__ flags)
{
    const int t = threadIdx.x;
    const int w = t >> 6, l = t & 63;
    const int g = blockIdx.x;
    const int Mt = w & 1;                // batch-tile
    const int p  = w >> 1;               // col-pair within block slice
    const int c16 = l & 15;
    const int k8  = (l >> 4) * 8;
    const int rbase = (l >> 4) * 4;      // D-layout row base

    const int col0 = g * 64 + p * 32 + c16;     // cti=0 col; cti=1 is +16

    // ---- B-frags (one-time): 2 ct x 16 kf = 128 VGPRs ----
    f16x8 wb[2][16];
#pragma unroll
    for (int cti = 0; cti < 2; cti++) {
        const float* wrow = Whh + (size_t)(col0 + cti * 16) * 512;
#pragma unroll
        for (int kf = 0; kf < 16; kf++) {
            float4 w0 = *(const float4*)(wrow + kf * 32 + k8);
            float4 w1 = *(const float4*)(wrow + kf * 32 + k8 + 4);
            f16x8 h;
            h[0] = (f16)w0.x; h[1] = (f16)w0.y; h[2] = (f16)w0.z; h[3] = (f16)w0.w;
            h[4] = (f16)w1.x; h[5] = (f16)w1.y; h[6] = (f16)w1.z; h[7] = (f16)w1.w;
            wb[cti][kf] = h;
        }
    }

    f16* hs0 = hstate;                   // [32][512], step-even h
    f16* hs1 = hstate + BATCH * HID;     // step-odd h

    // xp for step 0 (this lane's 8 outputs: 2 cols x 4 batch-rows)
    float xc[2][4];
#pragma unroll
    for (int cti = 0; cti < 2; cti++)
#pragma unroll
        for (int r = 0; r < 4; r++)
            xc[cti][r] = (float)xp[((size_t)(Mt * 16 + rbase + r) * SEQL) * 512
                                   + col0 + cti * 16];

    for (int s = 0; s < NSTEP; s++) {
        const f16* hcur = (s & 1) ? hs1 : hs0;
        f16*       hnxt = (s & 1) ? hs0 : hs1;

        if (s > 0) {   // wait until all peers published h_s
            if (t < NCOOP) {
                while (__hip_atomic_load(&flags[t * 16], __ATOMIC_ACQUIRE,
                                         __HIP_MEMORY_SCOPE_AGENT) < (unsigned)s)
                    __builtin_amdgcn_s_sleep(1);
            }
            __syncthreads();
            asm volatile("" ::: "memory");
        }

        // prefetch next step's xp (independent of h — full step of slack)
        int sn = (s + 1 < NSTEP) ? s + 1 : s;
        float xn[2][4];
#pragma unroll
        for (int cti = 0; cti < 2; cti++)
#pragma unroll
            for (int r = 0; r < 4; r++)
                xn[cti][r] = (float)xp[((size_t)(Mt * 16 + rbase + r) * SEQL + sn) * 512
                                       + col0 + cti * 16];

        // A-frags direct from global h-state (L2/LLC): row = batch = Mt*16+c16
        f16x8 af[16];
#pragma unroll
        for (int kf = 0; kf < 16; kf++)
            af[kf] = *(const f16x8*)&hcur[(Mt * 16 + c16) * HID + kf * 32 + k8];

        f32x4 a0 = (f32x4){0.f, 0.f, 0.f, 0.f}, a1 = a0;
#pragma unroll
        for (int kf = 0; kf < 16; kf++) {
            a0 = __builtin_amdgcn_mfma_f32_16x16x32_f16(af[kf], wb[0][kf], a0, 0, 0, 0);
            a1 = __builtin_amdgcn_mfma_f32_16x16x32_f16(af[kf], wb[1][kf], a1, 0, 0, 0);
        }

        // epilogue: D row = rbase + r (batch), col = col0 / col0+16
#pragma unroll
        for (int r = 0; r < 4; r++) {
            int batch = Mt * 16 + rbase + r;
            float v0 = a0[r] + xc[0][r];
            float v1 = a1[r] + xc[1][r];
            v0 = 1.f - 2.f / (__expf(2.f * v0) + 1.f);   // tanh, saturating
            v1 = 1.f - 2.f / (__expf(2.f * v1) + 1.f);
            hnxt[batch * HID + col0]      = (f16)v0;
            hnxt[batch * HID + col0 + 16] = (f16)v1;
        }
#pragma unroll
        for (int cti = 0; cti < 2; cti++)
#pragma unroll
            for (int r = 0; r < 4; r++) xc[cti][r] = xn[cti][r];

        __syncthreads();   // drains every wave's stores (vmcnt 0) before publish
        if (t == 0)
            __hip_atomic_store(&flags[g * 16], (unsigned)(s + 1),
                               __ATOMIC_RELEASE, __HIP_MEMORY_SCOPE_AGENT);
    }
    // final h (step 2048, even) sits in hs0 = hstate[0]; fc reads it directly
}

// ---------------------------------------------------------------------------
// Phase 2 fallback: exact r0 rnn (2447 us) — used only if ws too small.
// ---------------------------------------------------------------------------
#define P2_LDS_BYTES (2 * HID * 2 + 8 * 16 * 64 * 16)  // 133120

__global__ __launch_bounds__(512, 2) void rnn_kernel(
    const float* __restrict__ Whh, const f16* __restrict__ xp,
    f16* __restrict__ hfin)
{
    extern __shared__ __align__(16) char smem[];
    f16* hbuf0 = (f16*)smem;
    f16* hbuf1 = hbuf0 + HID;
    f16* ldsB  = hbuf1 + HID;

    const int t = threadIdx.x;
    const int wave = t >> 6, lane = t & 63;
    const int b = blockIdx.x;
    const int c_in = lane & 15;
    const int k8   = (lane >> 4) * 8;

    f16x8 wreg[48];
#pragma unroll
    for (int r = 0; r < 3; r++) {
        const float* wrow = Whh + (size_t)((wave * 4 + r) * 16 + c_in) * 512;
#pragma unroll
        for (int kf = 0; kf < 16; kf++) {
            float4 w0 = *(const float4*)(wrow + kf * 32 + k8);
            float4 w1 = *(const float4*)(wrow + kf * 32 + k8 + 4);
            f16x8 h;
            h[0] = (f16)w0.x; h[1] = (f16)w0.y; h[2] = (f16)w0.z; h[3] = (f16)w0.w;
            h[4] = (f16)w1.x; h[5] = (f16)w1.y; h[6] = (f16)w1.z; h[7] = (f16)w1.w;
            wreg[r * 16 + kf] = h;
        }
    }
    {
        const float* wrow = Whh + (size_t)((wave * 4 + 3) * 16 + c_in) * 512;
#pragma unroll
        for (int kf = 0; kf < 16; kf++) {
            float4 w0 = *(const float4*)(wrow + kf * 32 + k8);
            float4 w1 = *(const float4*)(wrow + kf * 32 + k8 + 4);
            f16x8 h;
            h[0] = (f16)w0.x; h[1] = (f16)w0.y; h[2] = (f16)w0.z; h[3] = (f16)w0.w;
            h[4] = (f16)w1.x; h[5] = (f16)w1.y; h[6] = (f16)w1.z; h[7] = (f16)w1.w;
            *(f16x8*)&ldsB[(size_t)wave * 8192 + kf * 512 + lane * 8] = h;
        }
    }
    hbuf0[t & (HID - 1)] = (f16)0.f;
    __syncthreads();

    const f16* xprow = xp + (size_t)b * SEQL * 512 + wave * 64 + lane;
    const int ldsb_base = wave * 8192 + lane * 8;

    float xv = (float)xprow[0];
    for (int s = 0; s < NSTEP; s++) {
        const f16* cur = (s & 1) ? hbuf1 : hbuf0;
        f16*       nxt = (s & 1) ? hbuf0 : hbuf1;
        int sn = (s + 1 < NSTEP) ? s + 1 : s;
        float xv_next = (float)xprow[(size_t)sn * 512];

        f32x4 a0 = (f32x4){0.f,0.f,0.f,0.f}, a1 = a0, a2 = a0, a3 = a0;
#pragma unroll
        for (int kf = 0; kf < 16; kf++) {
            f16x8 av = *(const f16x8*)&cur[kf * 32 + k8];
            a0 = __builtin_amdgcn_mfma_f32_16x16x32_f16(av, wreg[kf],      a0, 0, 0, 0);
            a1 = __builtin_amdgcn_mfma_f32_16x16x32_f16(av, wreg[16 + kf], a1, 0, 0, 0);
            a2 = __builtin_amdgcn_mfma_f32_16x16x32_f16(av, wreg[32 + kf], a2, 0, 0, 0);
            f16x8 bl = *(const f16x8*)&ldsB[ldsb_base + kf * 512];
            a3 = __builtin_amdgcn_mfma_f32_16x16x32_f16(av, bl, a3, 0, 0, 0);
        }
        int r = lane >> 4;
        float v = (r == 0) ? a0[0] : (r == 1) ? a1[0] : (r == 2) ? a2[0] : a3[0];
        v += xv;
        float e = __expf(2.f * v);
        v = 1.f - 2.f / (e + 1.f);
        nxt[wave * 64 + lane] = (f16)v;
        xv = xv_next;
        __syncthreads();
    }
    hfin[(size_t)b * 512 + t] = hbuf0[t & (HID - 1)];
}

// ---------------------------------------------------------------------------
// Phase 3: out[b][o] = sum_k h[b][k] * Wfc[o][k] + bfc[o]  (fp32 out)
// ---------------------------------------------------------------------------
#define P3_HS 520

__global__ __launch_bounds__(256, 2) void fc_kernel(
    const f16* __restrict__ hfin, const float* __restrict__ Wfc,
    const float* __restrict__ bfc, float* __restrict__ out)
{
    __shared__ __align__(16) f16 hs[BATCH * P3_HS];
    const int t = threadIdx.x;
    for (int i = 0; i < 64; i++) {
        int e = i * 256 + t;
        hs[(e >> 9) * P3_HS + (e & 511)] = hfin[e];
    }
    __syncthreads();

    const int bidx = t & 31;
    const int oi = t >> 5;
    const int o0 = blockIdx.x * 16;
    const int oA = o0 + oi, oB = o0 + oi + 8;
    const float* wA = Wfc + (size_t)oA * 512;
    const float* wB = Wfc + (size_t)oB * 512;

    float sA = 0.f, sB = 0.f;
#pragma unroll 4
    for (int kb = 0; kb < 64; kb++) {
        f16x8 hv = *(const f16x8*)&hs[bidx * P3_HS + kb * 8];
        float4 wa0 = *(const float4*)(wA + kb * 8);
        float4 wa1 = *(const float4*)(wA + kb * 8 + 4);
        float4 wb0 = *(const float4*)(wB + kb * 8);
        float4 wb1 = *(const float4*)(wB + kb * 8 + 4);
        float h0 = (float)hv[0], h1 = (float)hv[1], h2 = (float)hv[2], h3 = (float)hv[3];
        float h4 = (float)hv[4], h5 = (float)hv[5], h6 = (float)hv[6], h7 = (float)hv[7];
        sA += wa0.x*h0 + wa0.y*h1 + wa0.z*h2 + wa0.w*h3 + wa1.x*h4 + wa1.y*h5 + wa1.z*h6 + wa1.w*h7;
        sB += wb0.x*h0 + wb0.y*h1 + wb0.z*h2 + wb0.w*h3 + wb1.x*h4 + wb1.y*h5 + wb1.z*h6 + wb1.w*h7;
    }
    out[(size_t)bidx * 512 + oA] = sA + bfc[oA];
    out[(size_t)bidx * 512 + oB] = sB + bfc[oB];
}

// ---------------------------------------------------------------------------
extern "C" void kernel_launch(void* const* d_in, const int* in_sizes, int n_in,
                              void* d_out, int out_size, void* d_ws, size_t ws_size,
                              hipStream_t stream) {
    const float* x    = (const float*)d_in[0];
    const float* Wxh  = (const float*)d_in[1];
    const float* bxh  = (const float*)d_in[2];
    const float* Whh  = (const float*)d_in[3];
    const float* bhh  = (const float*)d_in[4];
    const float* bh   = (const float*)d_in[5];
    const float* Wfc  = (const float*)d_in[6];
    const float* bfc  = (const float*)d_in[7];
    float* outp = (float*)d_out;

    const size_t xp_bytes     = (size_t)BATCH * SEQL * 512 * 2;   // 64 MiB
    const size_t wf16_bytes   = (size_t)512 * 512 * 2;            // 512 KiB
    const size_t hstate_bytes = (size_t)2 * BATCH * HID * 2;      // 64 KiB
    const size_t flags_bytes  = 4096;

    f16* xp      = (f16*)d_ws;
    f16* wf16    = (f16*)((char*)d_ws + xp_bytes);
    f16* hstate  = (f16*)((char*)d_ws + xp_bytes + wf16_bytes);
    unsigned int* flags = (unsigned int*)((char*)d_ws + xp_bytes + wf16_bytes + hstate_bytes);

    if (ws_size >= xp_bytes + wf16_bytes + hstate_bytes + flags_bytes) {
        // fast path: f16 Wxh + cooperative column-split recurrence
        wcvt_kernel<<<128, 256, 0, stream>>>(Wxh, wf16, (unsigned int*)hstate, flags);
        xproj_f16_kernel<<<(BATCH * SEQL) / 64, 256, 0, stream>>>(
            x, wf16, bxh, bhh, bh, xp);
        rnn_coop_kernel<<<NCOOP, 256, 0, stream>>>(Whh, xp, hstate, flags);
        fc_kernel<<<32, 256, 0, stream>>>(hstate /* = final h */, Wfc, bfc, outp);
    } else {
        // fallback: r8 proven path (monolithic per-batch rnn)
        f16* hfin = (f16*)((char*)d_ws + xp_bytes);   // reuse wf16 slot
        hipFuncSetAttribute((const void*)rnn_kernel,
                            hipFuncAttributeMaxDynamicSharedMemorySize, 160 * 1024);
        xproj_kernel<<<(BATCH * SEQL) / 64, 256, 0, stream>>>(
            x, Wxh, bxh, bhh, bh, xp);
        rnn_kernel<<<BATCH, 512, P2_LDS_BYTES, stream>>>(Whh, xp, hfin);
        fc_kernel<<<32, 256, 0, stream>>>(hfin, Wfc, bfc, outp);
    }
}

// Round 10
// 2703.318 us; speedup vs baseline: 3.3479x; 3.3479x over previous
//
#include <hip/hip_runtime.h>

typedef _Float16 f16;
typedef _Float16 f16x8 __attribute__((ext_vector_type(8)));
typedef float    f32x4 __attribute__((ext_vector_type(4)));

#define NSTEP 2048
#define HID   512
#define BATCH 32
#define SEQL  2048

static __device__ __forceinline__ f16x8 cvt8(float4 a, float4 b) {
    f16x8 h;
    h[0] = (f16)a.x; h[1] = (f16)a.y; h[2] = (f16)a.z; h[3] = (f16)a.w;
    h[4] = (f16)b.x; h[5] = (f16)b.y; h[6] = (f16)b.z; h[7] = (f16)b.w;
    return h;
}

// ---------------------------------------------------------------------------
// One-time W_xh f32 -> f16 (r8, measured win: removes per-block cvt burden).
// ---------------------------------------------------------------------------
__global__ __launch_bounds__(256, 4) void wcvt_kernel(
    const float* __restrict__ W, f16* __restrict__ Wf)
{
    int i = (blockIdx.x * 256 + threadIdx.x) * 8;
    float4 a0 = *(const float4*)(W + i);
    float4 a1 = *(const float4*)(W + i + 4);
    *(f16x8*)&Wf[i] = cvt8(a0, a1);
}

// ---------------------------------------------------------------------------
// Phase 1 v3: xproj = x @ Wxh^T + bias, f16 out.  M=65536, N=512, K=512.
// Ladder-shape rebuild (compile-safe subset of m93/m97):
//   128x128 tile, 2048 blocks (bm = idx>>2, bn = idx&3 -> A-tile L2 reuse),
//   fragment-order LDS (lane-linear ds_read_b128, zero bank conflicts),
//   double-buffered, ONE barrier per K-chunk, acc 2x8 f32x4 = 64 VGPR/thread.
// Frag slot (g, lane) holds Mx[g*16 + (lane&15)][k0 + (lane>>4)*8 + j]:
//   staging thread t -> row r = t>>1, k-half h = t&1 covers quarters 2h,2h+1;
//   flat 16B idx = (r>>4)*64 + q*16 + (r&15).
// ---------------------------------------------------------------------------
__global__ __launch_bounds__(256, 2) void xproj_v3_kernel(
    const float* __restrict__ x, const f16* __restrict__ Wf16,
    const float* __restrict__ bxh, const float* __restrict__ bhh,
    const float* __restrict__ bh, f16* __restrict__ xp)
{
    __shared__ __align__(16) f16 Af[2][8 * 64 * 8];   // 8 KiB per buf
    __shared__ __align__(16) f16 Bf[2][8 * 64 * 8];

    const int t = threadIdx.x;
    const int wave = t >> 6, lane = t & 63;
    const size_t mbase = (size_t)(blockIdx.x >> 2) * 128;
    const int nbase = (blockIdx.x & 3) * 128;

    const int r_st = t >> 1;                 // staging row 0..127
    const int hh   = t & 1;                  // k-half -> quarters 2h, 2h+1
    const int dq0  = (r_st >> 4) * 64 + (2 * hh) * 16 + (r_st & 15);
    const int dq1  = dq0 + 16;

    f32x4 acc[2][8];
#pragma unroll
    for (int i = 0; i < 2; i++)
#pragma unroll
        for (int j = 0; j < 8; j++) acc[i][j] = (f32x4){0.f, 0.f, 0.f, 0.f};

    // ---- prologue: stage chunk 0 into buf 0 ----
    {
        const float* asrc = x + (mbase + r_st) * 512 + hh * 16;
        float4 a0 = *(const float4*)asrc;
        float4 a1 = *(const float4*)(asrc + 4);
        float4 a2 = *(const float4*)(asrc + 8);
        float4 a3 = *(const float4*)(asrc + 12);
        const f16* bsrc = Wf16 + (size_t)(nbase + r_st) * 512 + hh * 16;
        f16x8 hb0 = *(const f16x8*)bsrc;
        f16x8 hb1 = *(const f16x8*)(bsrc + 8);
        *(f16x8*)&Af[0][dq0 * 8] = cvt8(a0, a1);
        *(f16x8*)&Af[0][dq1 * 8] = cvt8(a2, a3);
        *(f16x8*)&Bf[0][dq0 * 8] = hb0;
        *(f16x8*)&Bf[0][dq1 * 8] = hb1;
    }
    __syncthreads();

    int buf = 0;
    for (int kc = 0; kc < 16; kc++) {
        const int nb = buf ^ 1;
        // issue next chunk's global loads first (latency hides under MFMAs)
        float4 a0, a1, a2, a3;
        f16x8 hb0, hb1;
        if (kc < 15) {
            const int kn = (kc + 1) * 32;
            const float* asrc = x + (mbase + r_st) * 512 + kn + hh * 16;
            a0 = *(const float4*)asrc;
            a1 = *(const float4*)(asrc + 4);
            a2 = *(const float4*)(asrc + 8);
            a3 = *(const float4*)(asrc + 12);
            const f16* bsrc = Wf16 + (size_t)(nbase + r_st) * 512 + kn + hh * 16;
            hb0 = *(const f16x8*)bsrc;
            hb1 = *(const f16x8*)(bsrc + 8);
        }

        // compute on current buffer: lane-linear frag reads (conflict-free)
        f16x8 af0 = *(const f16x8*)&Af[buf][((2 * wave + 0) * 64 + lane) * 8];
        f16x8 af1 = *(const f16x8*)&Af[buf][((2 * wave + 1) * 64 + lane) * 8];
#pragma unroll
        for (int ct = 0; ct < 8; ct++) {
            f16x8 bf = *(const f16x8*)&Bf[buf][(ct * 64 + lane) * 8];
            acc[0][ct] = __builtin_amdgcn_mfma_f32_16x16x32_f16(af0, bf, acc[0][ct], 0, 0, 0);
            acc[1][ct] = __builtin_amdgcn_mfma_f32_16x16x32_f16(af1, bf, acc[1][ct], 0, 0, 0);
        }

        // write next chunk into the other buffer (nobody reads it this iter)
        if (kc < 15) {
            *(f16x8*)&Af[nb][dq0 * 8] = cvt8(a0, a1);
            *(f16x8*)&Af[nb][dq1 * 8] = cvt8(a2, a3);
            *(f16x8*)&Bf[nb][dq0 * 8] = hb0;
            *(f16x8*)&Bf[nb][dq1 * 8] = hb1;
        }
        __syncthreads();   // one barrier: nb writes visible AND buf reads done
        buf = nb;
    }

    // epilogue: D col = lane&15 (n), row = (lane>>4)*4 + r (m)
#pragma unroll
    for (int ct = 0; ct < 8; ct++) {
        int n = nbase + ct * 16 + (lane & 15);
        float bias = bxh[n] + bhh[n] + bh[n];
#pragma unroll
        for (int i = 0; i < 2; i++) {
#pragma unroll
            for (int r = 0; r < 4; r++) {
                size_t m = mbase + (wave * 2 + i) * 16 + (lane >> 4) * 4 + r;
                xp[m * 512 + n] = (f16)(acc[i][ct][r] + bias);
            }
        }
    }
}

// f32-B fallback (original r0 xproj) — only if ws can't hold Wf16.
#define P1_AS 40

__global__ __launch_bounds__(256, 2) void xproj_kernel(
    const float* __restrict__ x, const float* __restrict__ Wxh,
    const float* __restrict__ bxh, const float* __restrict__ bhh,
    const float* __restrict__ bh, f16* __restrict__ xp)
{
    __shared__ __align__(16) f16 As[64 * P1_AS];
    __shared__ __align__(16) f16 Bs[512 * P1_AS];
    const int t = threadIdx.x;
    const int wave = t >> 6, lane = t & 63;
    const size_t mbase = (size_t)blockIdx.x * 64;
    f32x4 acc[4][8];
#pragma unroll
    for (int i = 0; i < 4; i++)
#pragma unroll
        for (int j = 0; j < 8; j++) acc[i][j] = (f32x4){0.f, 0.f, 0.f, 0.f};
    const int r_st = t >> 2;
    const int koff = (t & 3) * 8;
    for (int k0 = 0; k0 < 512; k0 += 32) {
        __syncthreads();
        {
            const float* src = x + (mbase + r_st) * 512 + k0 + koff;
            float4 a0 = *(const float4*)src;
            float4 a1 = *(const float4*)(src + 4);
            *(f16x8*)&As[r_st * P1_AS + koff] = cvt8(a0, a1);
        }
#pragma unroll
        for (int i = 0; i < 8; i++) {
            int n = r_st + i * 64;
            const float* src = Wxh + (size_t)n * 512 + k0 + koff;
            float4 b0 = *(const float4*)src;
            float4 b1 = *(const float4*)(src + 4);
            *(f16x8*)&Bs[n * P1_AS + koff] = cvt8(b0, b1);
        }
        __syncthreads();
        f16x8 af[4];
#pragma unroll
        for (int rt = 0; rt < 4; rt++)
            af[rt] = *(const f16x8*)&As[(rt * 16 + (lane & 15)) * P1_AS + (lane >> 4) * 8];
#pragma unroll
        for (int ct = 0; ct < 8; ct++) {
            f16x8 bf = *(const f16x8*)&Bs[((wave * 8 + ct) * 16 + (lane & 15)) * P1_AS + (lane >> 4) * 8];
#pragma unroll
            for (int rt = 0; rt < 4; rt++)
                acc[rt][ct] = __builtin_amdgcn_mfma_f32_16x16x32_f16(af[rt], bf, acc[rt][ct], 0, 0, 0);
        }
    }
#pragma unroll
    for (int ct = 0; ct < 8; ct++) {
        int n = wave * 128 + ct * 16 + (lane & 15);
        float bias = bxh[n] + bhh[n] + bh[n];
#pragma unroll
        for (int rt = 0; rt < 4; rt++) {
#pragma unroll
            for (int r = 0; r < 4; r++) {
                size_t m = mbase + rt * 16 + (lane >> 4) * 4 + r;
                xp[m * 512 + n] = (f16)(acc[rt][ct][r] + bias);
            }
        }
    }
}

// ---------------------------------------------------------------------------
// Phase 2: recurrence — EXACT r0/r8 kernel (measured 2441 us; ~85% of the
// per-batch-block paradigm's MFMA-issue bound).  Paradigm alternatives are
// measured dead ends: W_hh (512 KB) = entire per-CU VGPR file (r5-r7 spills),
// cross-CU h exchange = 2-4 us/step device-scope sync (r9: 8.5 ms).
// ---------------------------------------------------------------------------
#define P2_LDS_BYTES (2 * HID * 2 + 8 * 16 * 64 * 16)  // 133120

__global__ __launch_bounds__(512, 2) void rnn_kernel(
    const float* __restrict__ Whh, const f16* __restrict__ xp,
    f16* __restrict__ hfin)
{
    extern __shared__ __align__(16) char smem[];
    f16* hbuf0 = (f16*)smem;
    f16* hbuf1 = hbuf0 + HID;
    f16* ldsB  = hbuf1 + HID;

    const int t = threadIdx.x;
    const int wave = t >> 6, lane = t & 63;
    const int b = blockIdx.x;
    const int c_in = lane & 15;
    const int k8   = (lane >> 4) * 8;

    f16x8 wreg[48];
#pragma unroll
    for (int r = 0; r < 3; r++) {
        const float* wrow = Whh + (size_t)((wave * 4 + r) * 16 + c_in) * 512;
#pragma unroll
        for (int kf = 0; kf < 16; kf++) {
            float4 w0 = *(const float4*)(wrow + kf * 32 + k8);
            float4 w1 = *(const float4*)(wrow + kf * 32 + k8 + 4);
            wreg[r * 16 + kf] = cvt8(w0, w1);
        }
    }
    {
        const float* wrow = Whh + (size_t)((wave * 4 + 3) * 16 + c_in) * 512;
#pragma unroll
        for (int kf = 0; kf < 16; kf++) {
            float4 w0 = *(const float4*)(wrow + kf * 32 + k8);
            float4 w1 = *(const float4*)(wrow + kf * 32 + k8 + 4);
            *(f16x8*)&ldsB[(size_t)wave * 8192 + kf * 512 + lane * 8] = cvt8(w0, w1);
        }
    }
    hbuf0[t & (HID - 1)] = (f16)0.f;
    __syncthreads();

    const f16* xprow = xp + (size_t)b * SEQL * 512 + wave * 64 + lane;
    const int ldsb_base = wave * 8192 + lane * 8;

    float xv = (float)xprow[0];
    for (int s = 0; s < NSTEP; s++) {
        const f16* cur = (s & 1) ? hbuf1 : hbuf0;
        f16*       nxt = (s & 1) ? hbuf0 : hbuf1;
        int sn = (s + 1 < NSTEP) ? s + 1 : s;
        float xv_next = (float)xprow[(size_t)sn * 512];

        f32x4 a0 = (f32x4){0.f,0.f,0.f,0.f}, a1 = a0, a2 = a0, a3 = a0;
#pragma unroll
        for (int kf = 0; kf < 16; kf++) {
            f16x8 av = *(const f16x8*)&cur[kf * 32 + k8];
            a0 = __builtin_amdgcn_mfma_f32_16x16x32_f16(av, wreg[kf],      a0, 0, 0, 0);
            a1 = __builtin_amdgcn_mfma_f32_16x16x32_f16(av, wreg[16 + kf], a1, 0, 0, 0);
            a2 = __builtin_amdgcn_mfma_f32_16x16x32_f16(av, wreg[32 + kf], a2, 0, 0, 0);
            f16x8 bl = *(const f16x8*)&ldsB[ldsb_base + kf * 512];
            a3 = __builtin_amdgcn_mfma_f32_16x16x32_f16(av, bl, a3, 0, 0, 0);
        }
        int r = lane >> 4;
        float v = (r == 0) ? a0[0] : (r == 1) ? a1[0] : (r == 2) ? a2[0] : a3[0];
        v += xv;
        float e = __expf(2.f * v);
        v = 1.f - 2.f / (e + 1.f);
        nxt[wave * 64 + lane] = (f16)v;
        xv = xv_next;
        __syncthreads();
    }
    hfin[(size_t)b * 512 + t] = hbuf0[t & (HID - 1)];
}

// ---------------------------------------------------------------------------
// Phase 3: out[b][o] = sum_k h[b][k] * Wfc[o][k] + bfc[o]  (fp32 out)
// ---------------------------------------------------------------------------
#define P3_HS 520

__global__ __launch_bounds__(256, 2) void fc_kernel(
    const f16* __restrict__ hfin, const float* __restrict__ Wfc,
    const float* __restrict__ bfc, float* __restrict__ out)
{
    __shared__ __align__(16) f16 hs[BATCH * P3_HS];
    const int t = threadIdx.x;
    for (int i = 0; i < 64; i++) {
        int e = i * 256 + t;
        hs[(e >> 9) * P3_HS + (e & 511)] = hfin[e];
    }
    __syncthreads();

    const int bidx = t & 31;
    const int oi = t >> 5;
    const int o0 = blockIdx.x * 16;
    const int oA = o0 + oi, oB = o0 + oi + 8;
    const float* wA = Wfc + (size_t)oA * 512;
    const float* wB = Wfc + (size_t)oB * 512;

    float sA = 0.f, sB = 0.f;
#pragma unroll 4
    for (int kb = 0; kb < 64; kb++) {
        f16x8 hv = *(const f16x8*)&hs[bidx * P3_HS + kb * 8];
        float4 wa0 = *(const float4*)(wA + kb * 8);
        float4 wa1 = *(const float4*)(wA + kb * 8 + 4);
        float4 wb0 = *(const float4*)(wB + kb * 8);
        float4 wb1 = *(const float4*)(wB + kb * 8 + 4);
        float h0 = (float)hv[0], h1 = (float)hv[1], h2 = (float)hv[2], h3 = (float)hv[3];
        float h4 = (float)hv[4], h5 = (float)hv[5], h6 = (float)hv[6], h7 = (float)hv[7];
        sA += wa0.x*h0 + wa0.y*h1 + wa0.z*h2 + wa0.w*h3 + wa1.x*h4 + wa1.y*h5 + wa1.z*h6 + wa1.w*h7;
        sB += wb0.x*h0 + wb0.y*h1 + wb0.z*h2 + wb0.w*h3 + wb1.x*h4 + wb1.y*h5 + wb1.z*h6 + wb1.w*h7;
    }
    out[(size_t)bidx * 512 + oA] = sA + bfc[oA];
    out[(size_t)bidx * 512 + oB] = sB + bfc[oB];
}

// ---------------------------------------------------------------------------
extern "C" void kernel_launch(void* const* d_in, const int* in_sizes, int n_in,
                              void* d_out, int out_size, void* d_ws, size_t ws_size,
                              hipStream_t stream) {
    const float* x    = (const float*)d_in[0];
    const float* Wxh  = (const float*)d_in[1];
    const float* bxh  = (const float*)d_in[2];
    const float* Whh  = (const float*)d_in[3];
    const float* bhh  = (const float*)d_in[4];
    const float* bh   = (const float*)d_in[5];
    const float* Wfc  = (const float*)d_in[6];
    const float* bfc  = (const float*)d_in[7];
    float* outp = (float*)d_out;

    const size_t xp_bytes   = (size_t)BATCH * SEQL * 512 * 2;   // 64 MiB
    const size_t hfin_bytes = (size_t)BATCH * 512 * 2;          // 32 KiB
    const size_t wf16_bytes = (size_t)512 * 512 * 2;            // 512 KiB

    f16* xp   = (f16*)d_ws;
    f16* hfin = (f16*)((char*)d_ws + xp_bytes);
    f16* wf16 = (f16*)((char*)d_ws + xp_bytes + hfin_bytes);

    hipFuncSetAttribute((const void*)rnn_kernel,
                        hipFuncAttributeMaxDynamicSharedMemorySize, 160 * 1024);

    if (ws_size >= xp_bytes + hfin_bytes + wf16_bytes) {
        wcvt_kernel<<<128, 256, 0, stream>>>(Wxh, wf16);
        xproj_v3_kernel<<<(BATCH * SEQL / 128) * 4, 256, 0, stream>>>(
            x, wf16, bxh, bhh, bh, xp);
    } else {
        xproj_kernel<<<(BATCH * SEQL) / 64, 256, 0, stream>>>(
            x, Wxh, bxh, bhh, bh, xp);
    }
    rnn_kernel<<<BATCH, 512, P2_LDS_BYTES, stream>>>(Whh, xp, hfin);
    fc_kernel<<<32, 256, 0, stream>>>(hfin, Wfc, bfc, outp);
}